// Round 11
// baseline (264.701 us; speedup 1.0000x reference)
//
#include <hip/hip_runtime.h>
#include <math.h>

constexpr int N_ROWS = 1024;
constexpr int DDIM   = 512;
constexpr int C_CLS  = 100000;
constexpr float MARG = 0.4f;
constexpr int NPAN   = 1568;                // 64-col panels (main path), 1568*64 = 100352
constexpr int NT_FB  = 782;                 // fallback class tiles (BN=128, bf16 path)

typedef __attribute__((ext_vector_type(8))) short bf16x8;
typedef __attribute__((ext_vector_type(4))) float f32x4;
typedef __attribute__((ext_vector_type(4))) int   i32x4;
typedef __attribute__((ext_vector_type(8))) int   i32x8;
typedef __attribute__((address_space(1))) const void gvoid_t;
typedef __attribute__((address_space(3))) void lvoid_t;

__device__ __forceinline__ unsigned int f2bf(float x) {
    union { float f; unsigned int u; } v; v.f = x;
    return (v.u + 0x7FFFu + ((v.u >> 16) & 1u)) >> 16;   // RNE to bf16 bits
}

__device__ __forceinline__ float wave_sum(float s) {
    #pragma unroll
    for (int m = 1; m < 64; m <<= 1) s += __shfl_xor(s, m, 64);
    return s;
}

// ---- f32 -> e4m3fn ----
#if __has_builtin(__builtin_amdgcn_cvt_pk_fp8_f32)
__device__ __forceinline__ unsigned int pk4_e4m3(float a, float b, float c, float d) {
    unsigned int u = (unsigned int)__builtin_amdgcn_cvt_pk_fp8_f32(a, b, 0, false);
    u = (unsigned int)__builtin_amdgcn_cvt_pk_fp8_f32(c, d, (int)u, true);
    return u;
}
#else
__device__ __forceinline__ unsigned int sw_e4m3(float x) {
    x = fminf(fmaxf(x, -448.f), 448.f);
    unsigned int s = (x < 0.f) ? 0x80u : 0u;
    float ax = fabsf(x);
    if (ax < 7.8125e-3f) {
        int q = (int)rintf(ax * 512.f);
        if (q >= 8) return s | 0x08;
        return s | (unsigned int)q;
    }
    int e; float m = frexpf(ax, &e);
    int q = (int)rintf(m * 16.f);
    if (q == 16) { q = 8; e += 1; }
    int E = e - 1 + 7;
    if (E > 15) { E = 15; q = 14; }
    return s | ((unsigned int)E << 3) | (unsigned int)(q - 8);
}
__device__ __forceinline__ unsigned int pk4_e4m3(float a, float b, float c, float d) {
    return sw_e4m3(a) | (sw_e4m3(b) << 8) | (sw_e4m3(c) << 16) | (sw_e4m3(d) << 24);
}
#endif

// ---- e4m3fn -> f32 (manual, no-NaN inputs) ----
__device__ __forceinline__ float dec_e4m3(unsigned int b) {
    const unsigned int E = (b >> 3) & 15u, M = b & 7u;
    if (E) {
        union { unsigned int u; float f; } v;
        v.u = ((b & 0x80u) << 24) | ((E + 120u) << 23) | (M << 20);
        return v.f;
    }
    float d = (float)M * 0.001953125f;
    return (b & 0x80u) ? -d : d;
}

// ---- per-row norm of embs -> g[i], normalized fp8 ehat8 ----
__global__ __launch_bounds__(256) void prep_embs8(const float* __restrict__ embs,
                                                  float* __restrict__ g,
                                                  unsigned char* __restrict__ ehat8) {
    const int row  = blockIdx.x * 4 + (threadIdx.x >> 6);
    const int lane = threadIdx.x & 63;
    const float4* src = (const float4*)(embs + (size_t)row * DDIM + lane * 8);
    const float4 a = src[0], b = src[1];
    float ss = a.x*a.x + a.y*a.y + a.z*a.z + a.w*a.w
             + b.x*b.x + b.y*b.y + b.z*b.z + b.w*b.w;
    ss = wave_sum(ss);
    const float norm = sqrtf(ss);
    const float rn = 1.f / norm;
    if (lane == 0) {
        float gg = (norm - 20.f) / sqrtf(10000.f + 1e-3f) * 0.333f;
        gg = fminf(fmaxf(gg, -1.f), 1.f);
        g[row] = gg;
    }
    uint2 pk;
    pk.x = pk4_e4m3(a.x*rn, a.y*rn, a.z*rn, a.w*rn);
    pk.y = pk4_e4m3(b.x*rn, b.y*rn, b.z*rn, b.w*rn);
    *(uint2*)(ehat8 + (size_t)row * DDIM + lane * 8) = pk;
}

__device__ __forceinline__ i32x8 join8(i32x4 lo, i32x4 hi) {
    return __builtin_shufflevector(lo, hi, 0, 1, 2, 3, 4, 5, 6, 7);
}

// ==== fused norm + fp8 GEMM: block = 64-class panel x ALL 1024 rows ====
// Phase 0 (norm): stream 64 fp32 weight rows (128 KB HBM), compute norms,
//   convert to e4m3, write fragment-major into LDS (B resident whole block).
// Phases 1..32: 8 row-tiles x 4 K-tiles; A (ehat8, L2-hot) double-buffered
//   via global_load_lds + counted vmcnt(4) + raw barriers (no full drains).
// Per-row-tile epilogue: clamp + exp-sum -> psum[row][panel].
// B LDS layout (r8/r10-verified conflict-free fragment-major):
//   element (col c, k) at  t*8256 + sl*2048 + h*1024 + (q*16 + r)*16 + i
//   where t=k>>7, q=(k>>5)&3, h=(k>>4)&1, i=k&15, sl=(c-col0)>>4, r=(c-col0)&15.
//   (+64 B pad per K-section spreads write banks; reads are lane*16 contiguous.)
__global__ __launch_bounds__(256, 2) void gemm_fn(
        const float* __restrict__ weight,          // [100000][512] f32
        const unsigned char* __restrict__ ehat8,   // [1024][512] e4m3
        float* __restrict__ psum)                  // [1024][NPAN]
{
    __shared__ __align__(16) unsigned char Ab[2][16384];  // A dbuf: 2 x 16 KB
    __shared__ __align__(16) unsigned char Bf[32960];     // B full-K: 4 x (8192+64pad)
    __shared__ float redbuf[2][128];

    const int tid  = threadIdx.x;
    const int lane = tid & 63;
    const int wv   = tid >> 6;
    const int wr   = wv >> 1;     // 0..1 : 64-row half of row-tile
    const int wc   = wv & 1;      // 0..1 : 32-col half of panel
    const int r15  = lane & 15;
    const int q    = lane >> 4;

    // XCD swizzle: 1568 = 8*196; consecutive panels on one XCD (psum line locality)
    const int wgid = ((int)blockIdx.x & 7) * 196 + ((int)blockIdx.x >> 3);
    const int col0 = wgid * 64;

    // ---- norm + convert phase: wave wv owns 16 cols; per pass 4 cols ----
    const int j2 = lane >> 2;     // 0..15 : 32-float k-segment
    const int jr = lane & 3;      // row within 4-group
    const int tB = lane >> 4;     // K-tile of this lane's segment
    const int qB = j2 & 3;        // quarter within K-tile
    #pragma unroll
    for (int pass = 0; pass < 4; ++pass) {
        const int c_rel = wv * 16 + pass * 4 + jr;
        const int c     = col0 + c_rel;
        const bool oob  = (c >= C_CLS);
        const float* wb = weight + (size_t)(oob ? (C_CLS - 1) : c) * DDIM + j2 * 32;
        float4 v[8];
        #pragma unroll
        for (int i = 0; i < 8; ++i) v[i] = ((const float4*)wb)[i];
        float ss = 0.f;
        #pragma unroll
        for (int i = 0; i < 8; ++i)
            ss += v[i].x*v[i].x + v[i].y*v[i].y + v[i].z*v[i].z + v[i].w*v[i].w;
        ss += __shfl_xor(ss, 4, 64);  ss += __shfl_xor(ss, 8, 64);
        ss += __shfl_xor(ss, 16, 64); ss += __shfl_xor(ss, 32, 64);
        const float sc = oob ? 0.f : rsqrtf(ss);
        unsigned int u[8];
        #pragma unroll
        for (int i = 0; i < 8; ++i)
            u[i] = pk4_e4m3(v[i].x*sc, v[i].y*sc, v[i].z*sc, v[i].w*sc);
        unsigned char* wbase = Bf + tB * 8256 + wv * 2048 + (qB * 16 + pass * 4 + jr) * 16;
        i32x4 lo = {(int)u[0], (int)u[1], (int)u[2], (int)u[3]};
        i32x4 hi = {(int)u[4], (int)u[5], (int)u[6], (int)u[7]};
        *(i32x4*)(wbase)        = lo;   // h = 0
        *(i32x4*)(wbase + 1024) = hi;   // h = 1
    }
    asm volatile("s_waitcnt lgkmcnt(0)" ::: "memory");
    __builtin_amdgcn_sched_barrier(0);
    __builtin_amdgcn_s_barrier();

    f32x4 acc[4][2];
    #pragma unroll
    for (int m = 0; m < 4; ++m)
        #pragma unroll
        for (int n = 0; n < 2; ++n) acc[m][n] = f32x4{0.f, 0.f, 0.f, 0.f};

    // A staging: wave wv fills slabs {2wv,2wv+1} x halves (r10-verified pattern)
#define STAGEA(SLOT, RT, KT) do {                                                   \
    _Pragma("unroll")                                                               \
    for (int ss_ = 0; ss_ < 2; ++ss_) {                                             \
        const int sl_ = wv * 2 + ss_;                                               \
        const unsigned char* ga_ = ehat8 + (size_t)((RT) * 128 + 16 * sl_ + r15) * DDIM \
                                   + (KT) * 128 + q * 32;                           \
        __builtin_amdgcn_global_load_lds((gvoid_t*)ga_,                             \
            (lvoid_t*)(&Ab[SLOT][sl_ * 2048]), 16, 0, 0);                           \
        __builtin_amdgcn_global_load_lds((gvoid_t*)(ga_ + 16),                      \
            (lvoid_t*)(&Ab[SLOT][sl_ * 2048 + 1024]), 16, 0, 0);                    \
    }                                                                               \
} while (0)

    STAGEA(0, 0, 0);
    STAGEA(1, 0, 1);

    for (int p = 0; p < 32; ++p) {
        const int kt = p & 3, slot = p & 1;
        if (p == 31) { asm volatile("s_waitcnt vmcnt(0)" ::: "memory"); }
        else         { asm volatile("s_waitcnt vmcnt(4)" ::: "memory"); }
        __builtin_amdgcn_s_barrier();

        i32x4 bR[2][2];
        #pragma unroll
        for (int n = 0; n < 2; ++n) {
            bR[n][0] = *(const i32x4*)(Bf + kt * 8256 + (wc * 2 + n) * 2048 +        lane * 16);
            bR[n][1] = *(const i32x4*)(Bf + kt * 8256 + (wc * 2 + n) * 2048 + 1024 + lane * 16);
        }
        i32x4 aR[4][2];
        #pragma unroll
        for (int m = 0; m < 4; ++m) {
            aR[m][0] = *(const i32x4*)(&Ab[slot][(wr * 4 + m) * 2048 +        lane * 16]);
            aR[m][1] = *(const i32x4*)(&Ab[slot][(wr * 4 + m) * 2048 + 1024 + lane * 16]);
        }
        __builtin_amdgcn_s_setprio(1);
        #pragma unroll
        for (int m = 0; m < 4; ++m) {
            const i32x8 av = join8(aR[m][0], aR[m][1]);
            #pragma unroll
            for (int n = 0; n < 2; ++n)
                acc[m][n] = __builtin_amdgcn_mfma_scale_f32_16x16x128_f8f6f4(
                                av, join8(bR[n][0], bR[n][1]), acc[m][n], 0, 0, 0, 127, 0, 127);
        }
        __builtin_amdgcn_s_setprio(0);
        __builtin_amdgcn_s_barrier();   // all reads of A[slot] retired

        if (kt == 3) {
            // ---- per-row-tile epilogue (before stage issue: exact vmcnt ledger) ----
            const int rt = p >> 2;
            #pragma unroll
            for (int m = 0; m < 4; ++m) {
                #pragma unroll
                for (int j = 0; j < 4; ++j) {
                    const int lrow = wr * 64 + m * 16 + q * 4 + j;
                    float s = 0.f;
                    #pragma unroll
                    for (int n = 0; n < 2; ++n) {
                        float v = acc[m][n][j];
                        v = fminf(fmaxf(v, -0.999f), 0.999f);
                        s += __expf(64.f * v - 64.f);
                    }
                    #pragma unroll
                    for (int msk = 1; msk < 16; msk <<= 1) s += __shfl_xor(s, msk, 64);
                    if (r15 == 0) redbuf[wc][lrow] = s;
                }
            }
            asm volatile("s_waitcnt lgkmcnt(0)" ::: "memory");
            __builtin_amdgcn_sched_barrier(0);
            __builtin_amdgcn_s_barrier();
            if (tid < 128)
                psum[(size_t)(rt * 128 + tid) * NPAN + wgid] = redbuf[0][tid] + redbuf[1][tid];
            __builtin_amdgcn_s_barrier();   // protect redbuf for next row-tile
            #pragma unroll
            for (int m = 0; m < 4; ++m)
                #pragma unroll
                for (int n = 0; n < 2; ++n) acc[m][n] = f32x4{0.f, 0.f, 0.f, 0.f};
        }
        if (p <= 29) {
            const int pn = p + 2;
            STAGEA(pn & 1, pn >> 2, pn & 3);
        }
    }
#undef STAGEA
}

// ---- per-row combine: psum + fp32-recomputed label logit + margins ----
__global__ __launch_bounds__(256) void reduce_rowsF(
        const float* __restrict__ psum,            // [1024][NPAN]
        const unsigned char* __restrict__ ehat8,
        const float* __restrict__ weight,
        const int* __restrict__ labels,
        const float* __restrict__ g,
        float* __restrict__ losses) {
    const int row  = blockIdx.x * 4 + (threadIdx.x >> 6);
    const int lane = threadIdx.x & 63;
    const float* p = psum + (size_t)row * NPAN;
    float s = 0.f;
    for (int t = lane; t < NPAN; t += 64) s += p[t];
    const int lab = labels[row];
    const float4* wv4 = (const float4*)(weight + (size_t)lab * DDIM + lane * 8);
    const float4 wa = wv4[0], wb = wv4[1];
    const uint2 ea = *(const uint2*)(ehat8 + (size_t)row * DDIM + lane * 8);
    float wsq = wa.x*wa.x + wa.y*wa.y + wa.z*wa.z + wa.w*wa.w
              + wb.x*wb.x + wb.y*wb.y + wb.z*wb.z + wb.w*wb.w;
    float d = dec_e4m3( ea.x        & 0xFFu) * wa.x
            + dec_e4m3((ea.x >>  8) & 0xFFu) * wa.y
            + dec_e4m3((ea.x >> 16) & 0xFFu) * wa.z
            + dec_e4m3((ea.x >> 24) & 0xFFu) * wa.w
            + dec_e4m3( ea.y        & 0xFFu) * wb.x
            + dec_e4m3((ea.y >>  8) & 0xFFu) * wb.y
            + dec_e4m3((ea.y >> 16) & 0xFFu) * wb.z
            + dec_e4m3((ea.y >> 24) & 0xFFu) * wb.w;
    s   = wave_sum(s);
    d   = wave_sum(d);
    wsq = wave_sum(wsq);
    if (lane == 0) {
        const float v  = fminf(fmaxf(d * rsqrtf(wsq), -0.999f), 0.999f);
        const float gg = g[row];
        float th = acosf(v) - MARG * gg;
        th = fminf(fmaxf(th, 0.f), 3.14159265358979323846f);
        const float vm = cosf(th) - (1.f + MARG) * gg;
        s = s - __expf(64.f * v - 64.f) + __expf(64.f * vm - 64.f);
        losses[row] = 64.f + logf(s) - 64.f * vm;
    }
}

// ==== fallback path (bf16, round-1 verified) ====
__global__ __launch_bounds__(256) void prep_embs(const float* __restrict__ embs,
                                                 float* __restrict__ g,
                                                 unsigned short* __restrict__ ehat) {
    const int row  = blockIdx.x * 4 + (threadIdx.x >> 6);
    const int lane = threadIdx.x & 63;
    const float4* src = (const float4*)(embs + (size_t)row * DDIM + lane * 8);
    const float4 a = src[0], b = src[1];
    float ss = a.x*a.x + a.y*a.y + a.z*a.z + a.w*a.w
             + b.x*b.x + b.y*b.y + b.z*b.z + b.w*b.w;
    ss = wave_sum(ss);
    const float norm = sqrtf(ss);
    const float rn = 1.f / norm;
    if (lane == 0) {
        float gg = (norm - 20.f) / sqrtf(10000.f + 1e-3f) * 0.333f;
        gg = fminf(fmaxf(gg, -1.f), 1.f);
        g[row] = gg;
    }
    uint4 pk;
    pk.x = f2bf(a.x*rn) | (f2bf(a.y*rn) << 16);
    pk.y = f2bf(a.z*rn) | (f2bf(a.w*rn) << 16);
    pk.z = f2bf(b.x*rn) | (f2bf(b.y*rn) << 16);
    pk.w = f2bf(b.z*rn) | (f2bf(b.w*rn) << 16);
    *(uint4*)(ehat + (size_t)row * DDIM + lane * 8) = pk;
}

__global__ __launch_bounds__(256) void prep_wnorm(const float* __restrict__ w,
                                                  float* __restrict__ rnormw) {
    const int row  = blockIdx.x * 4 + (threadIdx.x >> 6);
    const int lane = threadIdx.x & 63;
    const float4* src = (const float4*)(w + (size_t)row * DDIM + lane * 8);
    const float4 a = src[0], b = src[1];
    float ss = a.x*a.x + a.y*a.y + a.z*a.z + a.w*a.w
             + b.x*b.x + b.y*b.y + b.z*b.z + b.w*b.w;
    ss = wave_sum(ss);
    if (lane == 0) rnormw[row] = 1.f / sqrtf(ss);
}

__global__ __launch_bounds__(256, 2) void gemm_fused_fb(
        const unsigned short* __restrict__ ehat,
        const float* __restrict__ weight,
        const float* __restrict__ rnormw,
        const int* __restrict__ labels,
        float* __restrict__ psum,
        float* __restrict__ dlab)
{
    constexpr int BM = 128, BN = 128, BK = 32;
    __shared__ __align__(16) unsigned short Asf[BM * BK];
    __shared__ __align__(16) unsigned short Bsf[BN * BK];
    __shared__ float redbuf[2][BM];

    const int bid    = blockIdx.x;
    const int tile_c = bid >> 3;
    const int tile_r = bid & 7;
    const int row0   = tile_r * BM;
    const int col0   = tile_c * BN;

    const int tid  = threadIdx.x;
    const int lane = tid & 63;
    const int wv   = tid >> 6;
    const int wr   = wv >> 1;
    const int wc   = wv & 1;

    f32x4 acc[4][4];
    #pragma unroll
    for (int m = 0; m < 4; ++m)
        #pragma unroll
        for (int n = 0; n < 4; ++n) acc[m][n] = f32x4{0.f, 0.f, 0.f, 0.f};

    const int kq    = tid & 7;
    const int brow0 = tid >> 3;
    int   cidx[4];
    float rnv[4];
    #pragma unroll
    for (int p = 0; p < 4; ++p) {
        int c = col0 + p * 32 + brow0;
        c = c < C_CLS ? c : C_CLS - 1;
        cidx[p] = c;
        rnv[p]  = rnormw[c];
    }

    for (int kt = 0; kt < DDIM / BK; ++kt) {
        const int kbase = kt * BK;
        #pragma unroll
        for (int call = 0; call < 2; ++call) {
            const int chunk = call * 256 + tid;
            const uint4 dd = *(const uint4*)(ehat + (size_t)(row0 + (chunk >> 2)) * DDIM
                                             + kbase + (chunk & 3) * 8);
            *(uint4*)(Asf + chunk * 8) = dd;
        }
        #pragma unroll
        for (int p = 0; p < 4; ++p) {
            const float4 wd = *(const float4*)(weight + (size_t)cidx[p] * DDIM + kbase + kq * 4);
            const float rr = rnv[p];
            const unsigned int lo = f2bf(wd.x * rr) | (f2bf(wd.y * rr) << 16);
            const unsigned int hi = f2bf(wd.z * rr) | (f2bf(wd.w * rr) << 16);
            *(uint2*)(Bsf + (p * 32 + brow0) * BK + kq * 4) = make_uint2(lo, hi);
        }
        __syncthreads();
        bf16x8 af[4], bfr[4];
        const int lr  = lane & 15;
        const int lko = (lane >> 4) * 8;
        #pragma unroll
        for (int m = 0; m < 4; ++m)
            af[m] = *(const bf16x8*)(Asf + (wr * 64 + m * 16 + lr) * BK + lko);
        #pragma unroll
        for (int n = 0; n < 4; ++n)
            bfr[n] = *(const bf16x8*)(Bsf + (wc * 64 + n * 16 + lr) * BK + lko);
        #pragma unroll
        for (int m = 0; m < 4; ++m)
            #pragma unroll
            for (int n = 0; n < 4; ++n)
                acc[m][n] = __builtin_amdgcn_mfma_f32_16x16x32_bf16(af[m], bfr[n], acc[m][n], 0, 0, 0);
        __syncthreads();
    }

    #pragma unroll
    for (int m = 0; m < 4; ++m) {
        #pragma unroll
        for (int j = 0; j < 4; ++j) {
            const int lrow  = wr * 64 + m * 16 + ((lane >> 4) << 2) + j;
            const int r_abs = row0 + lrow;
            const int lab   = labels[r_abs];
            float s = 0.f;
            #pragma unroll
            for (int n = 0; n < 4; ++n) {
                const int c_abs = col0 + wc * 64 + n * 16 + (lane & 15);
                float v = acc[m][n][j];
                v = fminf(fmaxf(v, -0.999f), 0.999f);
                if (c_abs == lab) dlab[r_abs] = v;
                if (c_abs < C_CLS) s += __expf(64.f * v - 64.f);
            }
            #pragma unroll
            for (int msk = 1; msk < 16; msk <<= 1) s += __shfl_xor(s, msk, 64);
            if ((lane & 15) == 0) redbuf[wc][lrow] = s;
        }
    }
    __syncthreads();
    for (int t = tid; t < BM; t += 256)
        psum[(size_t)(row0 + t) * NT_FB + tile_c] = redbuf[0][t] + redbuf[1][t];
}

__global__ __launch_bounds__(256) void reduce_rows(const float* __restrict__ psum,
                                                   const float* __restrict__ dlab,
                                                   const float* __restrict__ g,
                                                   float* __restrict__ losses, int nt) {
    const int row  = blockIdx.x * 4 + (threadIdx.x >> 6);
    const int lane = threadIdx.x & 63;
    const float* p = psum + (size_t)row * nt;
    float s = 0.f;
    for (int t = lane; t < nt; t += 64) s += p[t];
    s = wave_sum(s);
    if (lane == 0) {
        const float v  = dlab[row];
        const float gg = g[row];
        float th = acosf(v) - MARG * gg;
        th = fminf(fmaxf(th, 0.f), 3.14159265358979323846f);
        const float vm = cosf(th) - (1.f + MARG) * gg;
        s = s - __expf(64.f * v - 64.f) + __expf(64.f * vm - 64.f);
        losses[row] = 64.f + logf(s) - 64.f * vm;
    }
}

__global__ __launch_bounds__(256) void final_mean(const float* __restrict__ losses,
                                                  float* __restrict__ out) {
    const int tid = threadIdx.x;
    float s = 0.f;
    #pragma unroll
    for (int i = 0; i < 4; ++i) s += losses[tid + i * 256];
    s = wave_sum(s);
    __shared__ float red[4];
    if ((tid & 63) == 0) red[tid >> 6] = s;
    __syncthreads();
    if (tid == 0) out[0] = (red[0] + red[1] + red[2] + red[3]) * (1.f / 1024.f);
}

extern "C" void kernel_launch(void* const* d_in, const int* in_sizes, int n_in,
                              void* d_out, int out_size, void* d_ws, size_t ws_size,
                              hipStream_t stream) {
    const float* embs   = (const float*)d_in[0];
    const float* weight = (const float*)d_in[1];
    const int*   labels = (const int*)d_in[2];
    float* out = (float*)d_out;
    unsigned char* wsb = (unsigned char*)d_ws;

    // main-path layout (bytes): ehat8 | psum | g | losses  (~7 MB)
    const size_t EHAT8_B = (size_t)N_ROWS * DDIM;             // 524,288
    const size_t PSUM_B  = (size_t)N_ROWS * NPAN * 4;         // 6,422,528
    const size_t NEED_B  = EHAT8_B + PSUM_B + 2 * 4096;

    if (ws_size >= NEED_B) {
        unsigned char* ehat8 = wsb;
        float* psum   = (float*)(wsb + EHAT8_B);
        float* gbuf   = (float*)(wsb + EHAT8_B + PSUM_B);
        float* losses = gbuf + 1024;

        prep_embs8<<<N_ROWS / 4, 256, 0, stream>>>(embs, gbuf, ehat8);
        gemm_fn<<<NPAN, 256, 0, stream>>>(weight, ehat8, psum);
        reduce_rowsF<<<N_ROWS / 4, 256, 0, stream>>>(psum, ehat8, weight, labels, gbuf, losses);
        final_mean<<<1, 256, 0, stream>>>(losses, out);
    } else {
        float* ws = (float*)d_ws;
        float* rnormw = ws + 0;
        float* gbuf   = ws + 100352;
        float* dlab   = ws + 101376;
        float* losses = ws + 102400;
        unsigned short* ehat = (unsigned short*)(ws + 103424);
        float* psum   = ws + 103424 + 262144;

        prep_embs <<<N_ROWS / 4, 256, 0, stream>>>(embs, gbuf, ehat);
        prep_wnorm<<<C_CLS / 4, 256, 0, stream>>>(weight, rnormw);
        gemm_fused_fb<<<NT_FB * 8, 256, 0, stream>>>(ehat, weight, rnormw, labels, psum, dlab);
        reduce_rows<<<N_ROWS / 4, 256, 0, stream>>>(psum, dlab, gbuf, losses, NT_FB);
        final_mean<<<1, 256, 0, stream>>>(losses, out);
    }
}